// Round 6
// baseline (611.830 us; speedup 1.0000x reference)
//
#include <hip/hip_runtime.h>

#define IMG_H 512
#define IMG_W 512
#define VIEW_TAN_F 0.57735026918962576451f  // tan(30 deg)
#define NEARZ 0.1f
#define BIGF 1e10f

#define TILE 32
#define NTX (IMG_W / TILE)      // 16 tiles per row
#define NTILES (NTX * NTX)      // 256 tiles
#define RSPLITS 32              // blocks per tile; strided candidate ranges
#define RSHIFT 5                // log2(RSPLITS)
#define MAXSURV 128             // max survivors per block (= F/RSPLITS)
#define ZSPLIT 8                // blocks per tile for the zhi pass
#define HXF 0.0625f             // (TILE/2) * (2/IMG_W)
#define HYF 0.0625f

// Per-face data: 3 x float4 = {A0,B0,C0,A1},{B1,C1,A2,B2},{C2,Az,Bz,Cz}
// Edge coefficients premultiplied by sign(area): inside <=> w0,w1,w2 >= 0.
// z = Az*x + Bz*y + Cz (affine; division by area folded into coefficients).

__global__ void prep_faces(const float* __restrict__ verts,
                           const int* __restrict__ faces,
                           const float* __restrict__ tex,
                           const float* __restrict__ campos,
                           const float* __restrict__ camup,
                           float4* __restrict__ fd,
                           float* __restrict__ cols,
                           unsigned long long* __restrict__ zbuf,
                           unsigned* __restrict__ zhi,
                           int* __restrict__ done,
                           float* __restrict__ out,
                           int F)
{
    int gid = blockIdx.x * blockDim.x + threadIdx.x;

    if (out && gid == 0) out[0] = 0.0f;   // replaces hipMemsetAsync dispatch

    // zbuf + zhi + done init (grid-stride), replaces hipMemsetAsync dispatches
    if (zbuf) {
        const int P = IMG_H * IMG_W;
        for (int i = gid; i < P; i += gridDim.x * blockDim.x)
            zbuf[i] = ~0ull;
        if (gid < NTILES) {
            zhi[gid]  = 0x7F7FFFFFu;   // FLT_MAX bits (positive-float order)
            done[gid] = 0;
        }
    }

    int f = gid;
    if (f >= F) return;

    float ex = campos[0], ey = campos[1], ez = campos[2];
    float ux = camup[0], uy = camup[1], uz = camup[2];
    float zxv = -ex, zyv = -ey, zzv = -ez;
    float inv = 1.0f / (sqrtf(zxv*zxv + zyv*zyv + zzv*zzv) + 1e-12f);
    zxv *= inv; zyv *= inv; zzv *= inv;
    inv = 1.0f / (sqrtf(ux*ux + uy*uy + uz*uz) + 1e-12f);
    ux *= inv; uy *= inv; uz *= inv;
    float xxv = uy*zzv - uz*zyv;
    float xyv = uz*zxv - ux*zzv;
    float xzv = ux*zyv - uy*zxv;
    inv = 1.0f / (sqrtf(xxv*xxv + xyv*xyv + xzv*xzv) + 1e-12f);
    xxv *= inv; xyv *= inv; xzv *= inv;
    float yxv = zyv*xzv - zzv*xyv;
    float yyv = zzv*xxv - zxv*xzv;
    float yzv = zxv*xyv - zyv*xxv;

    float px_[3], py_[3], pz_[3];
    #pragma unroll
    for (int k = 0; k < 3; ++k) {
        int vi = faces[f*3 + k];
        float vx = verts[vi*3+0] - ex;
        float vy = verts[vi*3+1] - ey;
        float vz = verts[vi*3+2] - ez;
        float cx = xxv*vx + xyv*vy + xzv*vz;
        float cy = yxv*vx + yyv*vy + yzv*vz;
        float cz = zxv*vx + zyv*vy + zzv*vz;
        float denom = cz * VIEW_TAN_F + 1e-12f;
        px_[k] = cx / denom;
        py_[k] = cy / denom;
        pz_[k] = cz;
    }
    float x0 = px_[0], y0 = py_[0];
    float x1 = px_[1], y1 = py_[1];
    float x2 = px_[2], y2 = py_[2];
    float area = (x1-x0)*(y2-y0) - (y1-y0)*(x2-x0);
    bool valid = fabsf(area) > 1e-8f;
    float safe = valid ? area : 1.0f;
    float s = (area > 0.0f) ? 1.0f : -1.0f;

    float A0 = -(y2-y1), B0 = (x2-x1), C0 = (y2-y1)*x1 - (x2-x1)*y1;
    float A1 = -(y0-y2), B1 = (x0-x2), C1 = (y0-y2)*x2 - (x0-x2)*y2;
    float A2 = -(y1-y0), B2 = (x1-x0), C2 = (y1-y0)*x0 - (x1-x0)*y0;

    float invs = 1.0f / safe;
    float Az = (A0*pz_[0] + A1*pz_[1] + A2*pz_[2]) * invs;
    float Bz = (B0*pz_[0] + B1*pz_[1] + B2*pz_[2]) * invs;
    float Cz = (C0*pz_[0] + C1*pz_[1] + C2*pz_[2]) * invs;

    A0 *= s; B0 *= s; C0 *= s;
    A1 *= s; B1 *= s; C1 *= s;
    A2 *= s; B2 *= s; C2 *= s;

    if (!valid) {
        A0 = B0 = A1 = B1 = A2 = B2 = 0.0f;
        C0 = C1 = C2 = -1.0f;   // always fails inside + tile tests
        Az = Bz = 0.0f; Cz = 0.0f;
    }

    fd[f*3+0] = make_float4(A0, B0, C0, A1);
    fd[f*3+1] = make_float4(B1, C1, A2, B2);
    fd[f*3+2] = make_float4(C2, Az, Bz, Cz);

    float c0 = 0.0f, c1 = 0.0f, c2 = 0.0f;
    #pragma unroll
    for (int t = 0; t < 8; ++t) {
        c0 += tex[f*24 + t*3 + 0];
        c1 += tex[f*24 + t*3 + 1];
        c2 += tex[f*24 + t*3 + 2];
    }
    cols[f*3+0] = c0 * 0.125f;
    cols[f*3+1] = c1 * 0.125f;
    cols[f*3+2] = c2 * 0.125f;
}

// (tile, sub) blocks: zhi[tile] = min over faces that FULLY cover the tile
// rect (conservative rect test on affine edge/z functions) of rect-max z.
// ZSPLIT blocks share a tile (each scans F/ZSPLIT faces), merged via uint
// atomicMin (all values positive => uint order == float order).
__global__ __launch_bounds__(256) void zhi_tiles(
    const float4* __restrict__ fd, int F, unsigned* __restrict__ zhi)
{
    int b    = blockIdx.x;
    int sub  = b & (ZSPLIT - 1);
    int tile = b >> 3;               // log2(ZSPLIT)
    int tX = tile & (NTX - 1);
    int tY = tile >> 4;
    int tid = threadIdx.x;

    float cx = ((float)(tX * TILE + TILE/2)) * (2.0f / IMG_W) - 1.0f;
    float cy = 1.0f - ((float)(tY * TILE + TILE/2)) * (2.0f / IMG_H);

    int nz = (F + ZSPLIT - 1) / ZSPLIT;
    int f0 = sub * nz;
    int f1 = min(f0 + nz, F);

    float local = BIGF;
    for (int f = f0 + tid; f < f1; f += 256) {
        float4 q0 = fd[3*f + 0];
        float4 q1 = fd[3*f + 1];
        float4 q2 = fd[3*f + 2];
        float m0 = fabsf(q0.x)*HXF + fabsf(q0.y)*HYF;
        float m1 = fabsf(q0.w)*HXF + fabsf(q1.x)*HYF;
        float m2 = fabsf(q1.z)*HXF + fabsf(q1.w)*HYF;
        float e0 = fmaf(q0.x, cx, fmaf(q0.y, cy, q0.z));
        float e1 = fmaf(q0.w, cx, fmaf(q1.x, cy, q1.y));
        float e2 = fmaf(q1.z, cx, fmaf(q1.w, cy, q2.x));
        float zc = fmaf(q2.y, cx, fmaf(q2.z, cy, q2.w));
        float dz = fabsf(q2.y)*HXF + fabsf(q2.z)*HYF;
        float covmin = fminf(fminf(e0 - m0, e1 - m1), e2 - m2);
        if (covmin >= 1e-6f && (zc - dz) > NEARZ)
            local = fminf(local, zc + dz);
    }
    #pragma unroll
    for (int off = 32; off > 0; off >>= 1)
        local = fminf(local, __shfl_down(local, off, 64));

    __shared__ float wmin[4];
    int wid  = tid >> 6;
    int lane = tid & 63;
    if (lane == 0) wmin[wid] = local;
    __syncthreads();
    if (tid == 0) {
        float m = fminf(fminf(wmin[0], wmin[1]), fminf(wmin[2], wmin[3]));
        if (m < BIGF)
            atomicMin(&zhi[tile], __float_as_uint(m));
    }
}

// (tile, split) blocks. Each block scans a STRIDED subset of faces
// (f = split + RSPLITS*r), culls by tile overlap + hierarchical-z, compacts
// survivors + face data to LDS, rasterizes with a straight-line inner loop,
// merges winners via load-filtered packed-key atomicMin. The LAST of the
// tile's RSPLITS blocks (device-scope done-counter) then resolves the
// tile's 1024 pixels and atomicAdds the partial loss -- no separate
// resolve dispatch, and zbuf/cols are read L2-hot.
__global__ __launch_bounds__(256) void raster_resolve(
    const float4* __restrict__ fd,
    const unsigned* __restrict__ zhi,
    const float* __restrict__ cols,
    const float* __restrict__ imref,
    int F,
    unsigned long long* __restrict__ zbuf,
    int* __restrict__ done,
    float* __restrict__ out)
{
    __shared__ float4 sQ[MAXSURV][3];
    __shared__ int    sFi[MAXSURV];
    __shared__ int    sCnt;
    __shared__ int    sPrev;

    int b     = blockIdx.x;
    int split = b & (RSPLITS - 1);
    int tile  = b >> RSHIFT;
    int tX = tile & (NTX - 1);
    int tY = tile >> 4;
    int tid  = threadIdx.x;
    int lane = tid & 63;

    float cx = ((float)(tX * TILE + TILE/2)) * (2.0f / IMG_W) - 1.0f;
    float cy = 1.0f - ((float)(tY * TILE + TILE/2)) * (2.0f / IMG_H);

    float zHi = __uint_as_float(zhi[tile]) + 1e-4f;   // float-safety margin

    if (tid == 0) sCnt = 0;
    __syncthreads();

    // ---- scan my strided face subset, compact survivors (with data) ----
    int nf = F >> RSHIFT;              // F=4096 -> 128 (single round)
    for (int it = 0; it < nf; it += 256) {
        int r = it + tid;
        bool keep = false;
        float4 q0, q1, q2;
        int f = split + (r << RSHIFT);
        if (r < nf) {
            q0 = fd[3*f + 0];
            q1 = fd[3*f + 1];
            q2 = fd[3*f + 2];
            float e0 = fmaf(q0.x, cx, fmaf(q0.y, cy, q0.z)) + fabsf(q0.x)*HXF + fabsf(q0.y)*HYF;
            float e1 = fmaf(q0.w, cx, fmaf(q1.x, cy, q1.y)) + fabsf(q0.w)*HXF + fabsf(q1.x)*HYF;
            float e2 = fmaf(q1.z, cx, fmaf(q1.w, cy, q2.x)) + fabsf(q1.z)*HXF + fabsf(q1.w)*HYF;
            float zc = fmaf(q2.y, cx, fmaf(q2.z, cy, q2.w));
            float dz = fabsf(q2.y)*HXF + fabsf(q2.z)*HYF;
            keep = (fminf(fminf(e0, e1), e2) >= -1e-6f) && ((zc - dz) <= zHi);
        }
        unsigned long long mball = __ballot(keep);
        int wb = 0;
        if (lane == 0 && mball) wb = atomicAdd(&sCnt, __popcll(mball));
        wb = __shfl(wb, 0, 64);
        if (keep) {
            int pos = wb + __popcll(mball & ((1ull << lane) - 1ull));
            sQ[pos][0] = q0;
            sQ[pos][1] = q1;
            sQ[pos][2] = q2;
            sFi[pos] = f;
        }
    }
    __syncthreads();
    int n = sCnt;

    // ---- rasterize survivors: straight-line loop, 4px/thread ----
    int colp = tX * TILE + (tid & 31);
    int row0 = tY * TILE + (tid >> 5);   // rows row0 + 8k, k=0..3
    float x  = ((float)colp + 0.5f) * (2.0f / IMG_W) - 1.0f;
    float y0 = 1.0f - ((float)row0 + 0.5f) * (2.0f / IMG_H);

    float bz[4] = {BIGF, BIGF, BIGF, BIGF};
    int   bi[4] = {-1, -1, -1, -1};

    for (int s = 0; s < n; ++s) {
        float4 p0 = sQ[s][0], p1 = sQ[s][1], p2 = sQ[s][2];
        int fi = sFi[s];
        float w0x = fmaf(p0.x, x, p0.z);
        float w1x = fmaf(p0.w, x, p1.y);
        float w2x = fmaf(p1.z, x, p2.x);
        float zx  = fmaf(p2.y, x, p2.w);
        #pragma unroll
        for (int k = 0; k < 4; ++k) {
            float yk = y0 - (float)k * 0.03125f;   // 8 rows * 2/512
            float w0 = fmaf(p0.y, yk, w0x);
            float w1 = fmaf(p1.x, yk, w1x);
            float w2 = fmaf(p1.w, yk, w2x);
            float z  = fmaf(p2.z, yk, zx);
            bool hit = (fminf(fminf(w0, w1), w2) >= 0.0f) && (z > NEARZ);
            // strict-better, lowest-face-index tie-break (matches reference)
            bool better = hit && ((z < bz[k]) || (z == bz[k] && fi < bi[k]));
            if (better) { bz[k] = z; bi[k] = fi; }
        }
    }

    #pragma unroll
    for (int k = 0; k < 4; ++k) {
        if (bi[k] >= 0) {
            int p = (row0 + 8*k) * IMG_W + colp;
            unsigned long long key =
                ((unsigned long long)__float_as_uint(bz[k]) << 32) | (unsigned)bi[k];
            // load-filter: only pay the atomic if we might win (racy read is
            // safe -- the atomicMin remains authoritative)
            if (key < zbuf[p])
                atomicMin(&zbuf[p], key);
        }
    }

    // ---- last block of this tile resolves it ----
    __threadfence();                     // my zbuf atomics visible device-wide
    if (tid == 0) sPrev = atomicAdd(&done[tile], 1);
    __syncthreads();
    if (sPrev != RSPLITS - 1) return;

    const int HW = IMG_H * IMG_W;
    float loss = 0.0f;
    #pragma unroll
    for (int k = 0; k < 4; ++k) {
        int p = (row0 + 8*k) * IMG_W + colp;
        // atomicMin with ~0 never modifies but returns the current value via
        // L2 -- a coherent read immune to any stale L1 line from the
        // prefilter loads above.
        unsigned long long key = atomicMin(&zbuf[p], ~0ull);
        unsigned idx = (unsigned)(key & 0xffffffffull);
        float r = 0.0f, g = 0.0f, bl = 0.0f;
        if (idx != 0xffffffffu) {
            r  = cols[idx*3 + 0];
            g  = cols[idx*3 + 1];
            bl = cols[idx*3 + 2];
        }
        // image[:, ::-1] reverses the CHANNEL axis
        float d0 = bl - imref[0*HW + p];
        float d1 = g  - imref[1*HW + p];
        float d2 = r  - imref[2*HW + p];
        loss += fmaf(d0, d0, fmaf(d1, d1, d2*d2));
    }

    #pragma unroll
    for (int off = 32; off > 0; off >>= 1)
        loss += __shfl_down(loss, off, 64);

    __shared__ float wsum[4];
    int wid = tid >> 6;
    if (lane == 0) wsum[wid] = loss;
    __syncthreads();
    if (tid == 0)
        atomicAdd(out, wsum[0] + wsum[1] + wsum[2] + wsum[3]);
}

// Fallback (small ws): Round-1 monolithic kernel (validated absmax 0).
__global__ __launch_bounds__(256) void raster_loss_mono(
    const float4* __restrict__ fd,
    const float* __restrict__ cols,
    const float* __restrict__ imref,
    float* __restrict__ out, int F)
{
    int p = blockIdx.x * 256 + threadIdx.x;
    int col = p & (IMG_W - 1);
    float x = ((float)col + 0.5f) * (2.0f / IMG_W) - 1.0f;
    float y = 1.0f - ((float)(p >> 9) + 0.5f) * (2.0f / IMG_H);

    float bestz = BIGF;
    int besti = -1;
    for (int f = 0; f < F; ++f) {
        float4 q0 = fd[3*f + 0];
        float4 q1 = fd[3*f + 1];
        float4 q2 = fd[3*f + 2];
        float w0 = fmaf(q0.x, x, fmaf(q0.y, y, q0.z));
        float w1 = fmaf(q0.w, x, fmaf(q1.x, y, q1.y));
        float w2 = fmaf(q1.z, x, fmaf(q1.w, y, q2.x));
        float z  = fmaf(q2.y, x, fmaf(q2.z, y, q2.w));
        bool hit = (w0 >= 0.0f) & (w1 >= 0.0f) & (w2 >= 0.0f) & (z > NEARZ);
        float zm = hit ? z : BIGF;
        if (zm < bestz) { bestz = zm; besti = f; }
    }
    float r = 0.0f, g = 0.0f, bl = 0.0f;
    if (besti >= 0) { r = cols[besti*3]; g = cols[besti*3+1]; bl = cols[besti*3+2]; }
    const int HW = IMG_H * IMG_W;
    float d0 = bl - imref[p], d1 = g - imref[HW+p], d2 = r - imref[2*HW+p];
    float loss = fmaf(d0, d0, fmaf(d1, d1, d2*d2));
    #pragma unroll
    for (int off = 32; off > 0; off >>= 1)
        loss += __shfl_down(loss, off, 64);
    __shared__ float wsum[4];
    int wid = threadIdx.x >> 6, lane = threadIdx.x & 63;
    if (lane == 0) wsum[wid] = loss;
    __syncthreads();
    if (threadIdx.x == 0)
        atomicAdd(out, wsum[0] + wsum[1] + wsum[2] + wsum[3]);
}

extern "C" void kernel_launch(void* const* d_in, const int* in_sizes, int n_in,
                              void* d_out, int out_size, void* d_ws, size_t ws_size,
                              hipStream_t stream)
{
    const float* verts  = (const float*)d_in[0];
    const int*   faces  = (const int*)d_in[1];
    const float* tex    = (const float*)d_in[2];
    const float* campos = (const float*)d_in[3];
    const float* camup  = (const float*)d_in[4];
    const float* imref  = (const float*)d_in[5];
    int F = in_sizes[1] / 3;

    const int P = IMG_H * IMG_W;
    size_t zbytes  = (size_t)P * 8;
    size_t zhiB    = (size_t)NTILES * 4;
    size_t doneB   = (size_t)NTILES * 4;
    size_t fdbytes = (size_t)F * 3 * sizeof(float4);
    size_t cbytes  = (size_t)F * 3 * sizeof(float);
    float* out = (float*)d_out;

    if (ws_size >= zbytes + zhiB + doneB + fdbytes + cbytes &&
        (F % RSPLITS) == 0 && (F >> RSHIFT) <= MAXSURV) {
        char* w = (char*)d_ws;
        unsigned long long* zbuf = (unsigned long long*)w;          w += zbytes;
        unsigned* zhi  = (unsigned*)w;                              w += zhiB;
        int*      done = (int*)w;                                   w += doneB;
        float4*   fd   = (float4*)w;                                w += fdbytes;
        float*    cols = (float*)w;

        int pgrid = (F + 255)/256 > 512 ? (F + 255)/256 : 512;  // wide zbuf init
        prep_faces<<<pgrid, 256, 0, stream>>>(verts, faces, tex, campos, camup,
                                              fd, cols, zbuf, zhi, done, out, F);
        zhi_tiles<<<NTILES * ZSPLIT, 256, 0, stream>>>(fd, F, zhi);
        raster_resolve<<<NTILES * RSPLITS, 256, 0, stream>>>(fd, zhi, cols, imref,
                                                             F, zbuf, done, out);
    } else {
        hipMemsetAsync(d_out, 0, sizeof(float), stream);
        float4* fd   = (float4*)d_ws;
        float*  cols = (float*)((char*)d_ws + fdbytes);
        prep_faces<<<(F + 255)/256, 256, 0, stream>>>(verts, faces, tex, campos, camup, fd, cols,
                                                      (unsigned long long*)nullptr,
                                                      (unsigned*)nullptr, (int*)nullptr,
                                                      (float*)nullptr, F);
        raster_loss_mono<<<P/256, 256, 0, stream>>>(fd, cols, imref, out, F);
    }
}

// Round 7
// 99.342 us; speedup vs baseline: 6.1588x; 6.1588x over previous
//
#include <hip/hip_runtime.h>

#define IMG_H 512
#define IMG_W 512
#define VIEW_TAN_F 0.57735026918962576451f  // tan(30 deg)
#define NEARZ 0.1f
#define BIGF 1e10f

#define TILE 32
#define NTX (IMG_W / TILE)      // 16 tiles per row
#define NTILES (NTX * NTX)      // 256 tiles
#define RSPLITS 32              // blocks per tile; strided candidate ranges
#define RSHIFT 5                // log2(RSPLITS)
#define MAXSURV 128             // max survivors per block (= F/RSPLITS)
#define ZSPLIT 8                // blocks per tile for the zhi pass
#define HXF 0.0625f             // (TILE/2) * (2/IMG_W)
#define HYF 0.0625f

// Per-face data: 3 x float4 = {A0,B0,C0,A1},{B1,C1,A2,B2},{C2,Az,Bz,Cz}
// Edge coefficients premultiplied by sign(area): inside <=> w0,w1,w2 >= 0.
// z = Az*x + Bz*y + Cz (affine; division by area folded into coefficients).

__global__ void prep_faces(const float* __restrict__ verts,
                           const int* __restrict__ faces,
                           const float* __restrict__ tex,
                           const float* __restrict__ campos,
                           const float* __restrict__ camup,
                           float4* __restrict__ fd,
                           float* __restrict__ cols,
                           unsigned long long* __restrict__ zbuf,
                           unsigned* __restrict__ zhi,
                           float* __restrict__ out,
                           int F)
{
    int gid = blockIdx.x * blockDim.x + threadIdx.x;

    if (out && gid == 0) out[0] = 0.0f;   // replaces hipMemsetAsync dispatch

    // zbuf + zhi init (grid-stride), replaces hipMemsetAsync dispatches
    if (zbuf) {
        const int P = IMG_H * IMG_W;
        for (int i = gid; i < P; i += gridDim.x * blockDim.x)
            zbuf[i] = ~0ull;
        if (gid < NTILES)
            zhi[gid] = 0x7F7FFFFFu;    // FLT_MAX bits (positive-float order)
    }

    int f = gid;
    if (f >= F) return;

    float ex = campos[0], ey = campos[1], ez = campos[2];
    float ux = camup[0], uy = camup[1], uz = camup[2];
    float zxv = -ex, zyv = -ey, zzv = -ez;
    float inv = 1.0f / (sqrtf(zxv*zxv + zyv*zyv + zzv*zzv) + 1e-12f);
    zxv *= inv; zyv *= inv; zzv *= inv;
    inv = 1.0f / (sqrtf(ux*ux + uy*uy + uz*uz) + 1e-12f);
    ux *= inv; uy *= inv; uz *= inv;
    float xxv = uy*zzv - uz*zyv;
    float xyv = uz*zxv - ux*zzv;
    float xzv = ux*zyv - uy*zxv;
    inv = 1.0f / (sqrtf(xxv*xxv + xyv*xyv + xzv*xzv) + 1e-12f);
    xxv *= inv; xyv *= inv; xzv *= inv;
    float yxv = zyv*xzv - zzv*xyv;
    float yyv = zzv*xxv - zxv*xzv;
    float yzv = zxv*xyv - zyv*xxv;

    float px_[3], py_[3], pz_[3];
    #pragma unroll
    for (int k = 0; k < 3; ++k) {
        int vi = faces[f*3 + k];
        float vx = verts[vi*3+0] - ex;
        float vy = verts[vi*3+1] - ey;
        float vz = verts[vi*3+2] - ez;
        float cx = xxv*vx + xyv*vy + xzv*vz;
        float cy = yxv*vx + yyv*vy + yzv*vz;
        float cz = zxv*vx + zyv*vy + zzv*vz;
        float denom = cz * VIEW_TAN_F + 1e-12f;
        px_[k] = cx / denom;
        py_[k] = cy / denom;
        pz_[k] = cz;
    }
    float x0 = px_[0], y0 = py_[0];
    float x1 = px_[1], y1 = py_[1];
    float x2 = px_[2], y2 = py_[2];
    float area = (x1-x0)*(y2-y0) - (y1-y0)*(x2-x0);
    bool valid = fabsf(area) > 1e-8f;
    float safe = valid ? area : 1.0f;
    float s = (area > 0.0f) ? 1.0f : -1.0f;

    float A0 = -(y2-y1), B0 = (x2-x1), C0 = (y2-y1)*x1 - (x2-x1)*y1;
    float A1 = -(y0-y2), B1 = (x0-x2), C1 = (y0-y2)*x2 - (x0-x2)*y2;
    float A2 = -(y1-y0), B2 = (x1-x0), C2 = (y1-y0)*x0 - (x1-x0)*y0;

    float invs = 1.0f / safe;
    float Az = (A0*pz_[0] + A1*pz_[1] + A2*pz_[2]) * invs;
    float Bz = (B0*pz_[0] + B1*pz_[1] + B2*pz_[2]) * invs;
    float Cz = (C0*pz_[0] + C1*pz_[1] + C2*pz_[2]) * invs;

    A0 *= s; B0 *= s; C0 *= s;
    A1 *= s; B1 *= s; C1 *= s;
    A2 *= s; B2 *= s; C2 *= s;

    if (!valid) {
        A0 = B0 = A1 = B1 = A2 = B2 = 0.0f;
        C0 = C1 = C2 = -1.0f;   // always fails inside + tile tests
        Az = Bz = 0.0f; Cz = 0.0f;
    }

    fd[f*3+0] = make_float4(A0, B0, C0, A1);
    fd[f*3+1] = make_float4(B1, C1, A2, B2);
    fd[f*3+2] = make_float4(C2, Az, Bz, Cz);

    float c0 = 0.0f, c1 = 0.0f, c2 = 0.0f;
    #pragma unroll
    for (int t = 0; t < 8; ++t) {
        c0 += tex[f*24 + t*3 + 0];
        c1 += tex[f*24 + t*3 + 1];
        c2 += tex[f*24 + t*3 + 2];
    }
    cols[f*3+0] = c0 * 0.125f;
    cols[f*3+1] = c1 * 0.125f;
    cols[f*3+2] = c2 * 0.125f;
}

// (tile, sub) blocks: zhi[tile] = min over faces that FULLY cover the tile
// rect (conservative rect test on affine edge/z functions) of rect-max z.
// ZSPLIT blocks share a tile (each scans F/ZSPLIT faces), merged via uint
// atomicMin (all values positive => uint order == float order).
__global__ __launch_bounds__(256) void zhi_tiles(
    const float4* __restrict__ fd, int F, unsigned* __restrict__ zhi)
{
    int b    = blockIdx.x;
    int sub  = b & (ZSPLIT - 1);
    int tile = b >> 3;               // log2(ZSPLIT)
    int tX = tile & (NTX - 1);
    int tY = tile >> 4;
    int tid = threadIdx.x;

    float cx = ((float)(tX * TILE + TILE/2)) * (2.0f / IMG_W) - 1.0f;
    float cy = 1.0f - ((float)(tY * TILE + TILE/2)) * (2.0f / IMG_H);

    int nz = (F + ZSPLIT - 1) / ZSPLIT;
    int f0 = sub * nz;
    int f1 = min(f0 + nz, F);

    float local = BIGF;
    for (int f = f0 + tid; f < f1; f += 256) {
        float4 q0 = fd[3*f + 0];
        float4 q1 = fd[3*f + 1];
        float4 q2 = fd[3*f + 2];
        float m0 = fabsf(q0.x)*HXF + fabsf(q0.y)*HYF;
        float m1 = fabsf(q0.w)*HXF + fabsf(q1.x)*HYF;
        float m2 = fabsf(q1.z)*HXF + fabsf(q1.w)*HYF;
        float e0 = fmaf(q0.x, cx, fmaf(q0.y, cy, q0.z));
        float e1 = fmaf(q0.w, cx, fmaf(q1.x, cy, q1.y));
        float e2 = fmaf(q1.z, cx, fmaf(q1.w, cy, q2.x));
        float zc = fmaf(q2.y, cx, fmaf(q2.z, cy, q2.w));
        float dz = fabsf(q2.y)*HXF + fabsf(q2.z)*HYF;
        float covmin = fminf(fminf(e0 - m0, e1 - m1), e2 - m2);
        if (covmin >= 1e-6f && (zc - dz) > NEARZ)
            local = fminf(local, zc + dz);
    }
    #pragma unroll
    for (int off = 32; off > 0; off >>= 1)
        local = fminf(local, __shfl_down(local, off, 64));

    __shared__ float wmin[4];
    int wid  = tid >> 6;
    int lane = tid & 63;
    if (lane == 0) wmin[wid] = local;
    __syncthreads();
    if (tid == 0) {
        float m = fminf(fminf(wmin[0], wmin[1]), fminf(wmin[2], wmin[3]));
        if (m < BIGF)
            atomicMin(&zhi[tile], __float_as_uint(m));
    }
}

// (tile, split) blocks. Each block scans a STRIDED subset of faces
// (f = split + RSPLITS*r), culls by tile overlap + hierarchical-z, compacts
// survivors + face data to LDS, then rasterizes with a straight-line
// (branch-free) inner loop so the compiler can software-pipeline the LDS
// reads. Winner per pixel merged via load-filtered packed-key atomicMin.
__global__ __launch_bounds__(256) void raster_fused(
    const float4* __restrict__ fd,
    const unsigned* __restrict__ zhi,
    int F,
    unsigned long long* __restrict__ zbuf)
{
    __shared__ float4 sQ[MAXSURV][3];
    __shared__ int    sFi[MAXSURV];
    __shared__ int    sCnt;

    int b     = blockIdx.x;
    int split = b & (RSPLITS - 1);
    int tile  = b >> RSHIFT;
    int tX = tile & (NTX - 1);
    int tY = tile >> 4;
    int tid  = threadIdx.x;
    int lane = tid & 63;

    float cx = ((float)(tX * TILE + TILE/2)) * (2.0f / IMG_W) - 1.0f;
    float cy = 1.0f - ((float)(tY * TILE + TILE/2)) * (2.0f / IMG_H);

    float zHi = __uint_as_float(zhi[tile]) + 1e-4f;   // float-safety margin

    if (tid == 0) sCnt = 0;
    __syncthreads();

    // ---- scan my strided face subset, compact survivors (with data) ----
    int nf = F >> RSHIFT;              // F=4096 -> 128 (single round)
    for (int it = 0; it < nf; it += 256) {
        int r = it + tid;
        bool keep = false;
        float4 q0, q1, q2;
        int f = split + (r << RSHIFT);
        if (r < nf) {
            q0 = fd[3*f + 0];
            q1 = fd[3*f + 1];
            q2 = fd[3*f + 2];
            float e0 = fmaf(q0.x, cx, fmaf(q0.y, cy, q0.z)) + fabsf(q0.x)*HXF + fabsf(q0.y)*HYF;
            float e1 = fmaf(q0.w, cx, fmaf(q1.x, cy, q1.y)) + fabsf(q0.w)*HXF + fabsf(q1.x)*HYF;
            float e2 = fmaf(q1.z, cx, fmaf(q1.w, cy, q2.x)) + fabsf(q1.z)*HXF + fabsf(q1.w)*HYF;
            float zc = fmaf(q2.y, cx, fmaf(q2.z, cy, q2.w));
            float dz = fabsf(q2.y)*HXF + fabsf(q2.z)*HYF;
            keep = (fminf(fminf(e0, e1), e2) >= -1e-6f) && ((zc - dz) <= zHi);
        }
        unsigned long long mball = __ballot(keep);
        int wb = 0;
        if (lane == 0 && mball) wb = atomicAdd(&sCnt, __popcll(mball));
        wb = __shfl(wb, 0, 64);
        if (keep) {
            int pos = wb + __popcll(mball & ((1ull << lane) - 1ull));
            sQ[pos][0] = q0;
            sQ[pos][1] = q1;
            sQ[pos][2] = q2;
            sFi[pos] = f;
        }
    }
    __syncthreads();
    int n = sCnt;
    if (n == 0) return;                // block-uniform

    // ---- rasterize survivors: straight-line loop, 4px/thread ----
    int colp = tX * TILE + (tid & 31);
    int row0 = tY * TILE + (tid >> 5);   // rows row0 + 8k, k=0..3
    float x  = ((float)colp + 0.5f) * (2.0f / IMG_W) - 1.0f;
    float y0 = 1.0f - ((float)row0 + 0.5f) * (2.0f / IMG_H);

    float bz[4] = {BIGF, BIGF, BIGF, BIGF};
    int   bi[4] = {-1, -1, -1, -1};

    for (int s = 0; s < n; ++s) {
        float4 p0 = sQ[s][0], p1 = sQ[s][1], p2 = sQ[s][2];
        int fi = sFi[s];
        float w0x = fmaf(p0.x, x, p0.z);
        float w1x = fmaf(p0.w, x, p1.y);
        float w2x = fmaf(p1.z, x, p2.x);
        float zx  = fmaf(p2.y, x, p2.w);
        #pragma unroll
        for (int k = 0; k < 4; ++k) {
            float yk = y0 - (float)k * 0.03125f;   // 8 rows * 2/512
            float w0 = fmaf(p0.y, yk, w0x);
            float w1 = fmaf(p1.x, yk, w1x);
            float w2 = fmaf(p1.w, yk, w2x);
            float z  = fmaf(p2.z, yk, zx);
            bool hit = (fminf(fminf(w0, w1), w2) >= 0.0f) && (z > NEARZ);
            // strict-better, lowest-face-index tie-break (matches reference)
            bool better = hit && ((z < bz[k]) || (z == bz[k] && fi < bi[k]));
            if (better) { bz[k] = z; bi[k] = fi; }
        }
    }

    #pragma unroll
    for (int k = 0; k < 4; ++k) {
        if (bi[k] >= 0) {
            int p = (row0 + 8*k) * IMG_W + colp;
            unsigned long long key =
                ((unsigned long long)__float_as_uint(bz[k]) << 32) | (unsigned)bi[k];
            // load-filter: only pay the atomic if we might win (racy read is
            // safe -- the atomicMin remains authoritative)
            if (key < zbuf[p])
                atomicMin(&zbuf[p], key);
        }
    }
}

// 4 px/thread (strided): 256 blocks -> 256 final atomics instead of 1024.
__global__ __launch_bounds__(256) void resolve_loss(
    const unsigned long long* __restrict__ zbuf,
    const float* __restrict__ cols,
    const float* __restrict__ imref,
    float* __restrict__ out)
{
    const int HW = IMG_H * IMG_W;
    int base = blockIdx.x * 256 + threadIdx.x;
    float loss = 0.0f;
    #pragma unroll
    for (int q = 0; q < 4; ++q) {
        int p = base + q * (HW / 4);
        unsigned long long key = zbuf[p];
        unsigned idx = (unsigned)(key & 0xffffffffull);
        float r = 0.0f, g = 0.0f, bl = 0.0f;
        if (idx != 0xffffffffu) {
            r  = cols[idx*3 + 0];
            g  = cols[idx*3 + 1];
            bl = cols[idx*3 + 2];
        }
        // image[:, ::-1] reverses the CHANNEL axis
        float d0 = bl - imref[0*HW + p];
        float d1 = g  - imref[1*HW + p];
        float d2 = r  - imref[2*HW + p];
        loss += fmaf(d0, d0, fmaf(d1, d1, d2*d2));
    }

    #pragma unroll
    for (int off = 32; off > 0; off >>= 1)
        loss += __shfl_down(loss, off, 64);

    __shared__ float wsum[4];
    int wid  = threadIdx.x >> 6;
    int lane = threadIdx.x & 63;
    if (lane == 0) wsum[wid] = loss;
    __syncthreads();
    if (threadIdx.x == 0)
        atomicAdd(out, wsum[0] + wsum[1] + wsum[2] + wsum[3]);
}

// Fallback (small ws): Round-1 monolithic kernel (validated absmax 0).
__global__ __launch_bounds__(256) void raster_loss_mono(
    const float4* __restrict__ fd,
    const float* __restrict__ cols,
    const float* __restrict__ imref,
    float* __restrict__ out, int F)
{
    int p = blockIdx.x * 256 + threadIdx.x;
    int col = p & (IMG_W - 1);
    float x = ((float)col + 0.5f) * (2.0f / IMG_W) - 1.0f;
    float y = 1.0f - ((float)(p >> 9) + 0.5f) * (2.0f / IMG_H);

    float bestz = BIGF;
    int besti = -1;
    for (int f = 0; f < F; ++f) {
        float4 q0 = fd[3*f + 0];
        float4 q1 = fd[3*f + 1];
        float4 q2 = fd[3*f + 2];
        float w0 = fmaf(q0.x, x, fmaf(q0.y, y, q0.z));
        float w1 = fmaf(q0.w, x, fmaf(q1.x, y, q1.y));
        float w2 = fmaf(q1.z, x, fmaf(q1.w, y, q2.x));
        float z  = fmaf(q2.y, x, fmaf(q2.z, y, q2.w));
        bool hit = (w0 >= 0.0f) & (w1 >= 0.0f) & (w2 >= 0.0f) & (z > NEARZ);
        float zm = hit ? z : BIGF;
        if (zm < bestz) { bestz = zm; besti = f; }
    }
    float r = 0.0f, g = 0.0f, bl = 0.0f;
    if (besti >= 0) { r = cols[besti*3]; g = cols[besti*3+1]; bl = cols[besti*3+2]; }
    const int HW = IMG_H * IMG_W;
    float d0 = bl - imref[p], d1 = g - imref[HW+p], d2 = r - imref[2*HW+p];
    float loss = fmaf(d0, d0, fmaf(d1, d1, d2*d2));
    #pragma unroll
    for (int off = 32; off > 0; off >>= 1)
        loss += __shfl_down(loss, off, 64);
    __shared__ float wsum[4];
    int wid = threadIdx.x >> 6, lane = threadIdx.x & 63;
    if (lane == 0) wsum[wid] = loss;
    __syncthreads();
    if (threadIdx.x == 0)
        atomicAdd(out, wsum[0] + wsum[1] + wsum[2] + wsum[3]);
}

extern "C" void kernel_launch(void* const* d_in, const int* in_sizes, int n_in,
                              void* d_out, int out_size, void* d_ws, size_t ws_size,
                              hipStream_t stream)
{
    const float* verts  = (const float*)d_in[0];
    const int*   faces  = (const int*)d_in[1];
    const float* tex    = (const float*)d_in[2];
    const float* campos = (const float*)d_in[3];
    const float* camup  = (const float*)d_in[4];
    const float* imref  = (const float*)d_in[5];
    int F = in_sizes[1] / 3;

    const int P = IMG_H * IMG_W;
    size_t zbytes  = (size_t)P * 8;
    size_t zhiB    = (size_t)NTILES * 4;
    size_t fdbytes = (size_t)F * 3 * sizeof(float4);
    size_t cbytes  = (size_t)F * 3 * sizeof(float);
    float* out = (float*)d_out;

    if (ws_size >= zbytes + zhiB + fdbytes + cbytes &&
        (F % RSPLITS) == 0 && (F >> RSHIFT) <= MAXSURV && (P % 1024) == 0) {
        char* w = (char*)d_ws;
        unsigned long long* zbuf = (unsigned long long*)w;          w += zbytes;
        unsigned* zhi  = (unsigned*)w;                              w += zhiB;
        float4*   fd   = (float4*)w;                                w += fdbytes;
        float*    cols = (float*)w;

        int pgrid = (F + 255)/256 > 512 ? (F + 255)/256 : 512;  // wide zbuf init
        prep_faces<<<pgrid, 256, 0, stream>>>(verts, faces, tex, campos, camup,
                                              fd, cols, zbuf, zhi, out, F);
        zhi_tiles<<<NTILES * ZSPLIT, 256, 0, stream>>>(fd, F, zhi);
        raster_fused<<<NTILES * RSPLITS, 256, 0, stream>>>(fd, zhi, F, zbuf);
        resolve_loss<<<P/1024, 256, 0, stream>>>(zbuf, cols, imref, out);
    } else {
        hipMemsetAsync(d_out, 0, sizeof(float), stream);
        float4* fd   = (float4*)d_ws;
        float*  cols = (float*)((char*)d_ws + fdbytes);
        prep_faces<<<(F + 255)/256, 256, 0, stream>>>(verts, faces, tex, campos, camup, fd, cols,
                                                      (unsigned long long*)nullptr,
                                                      (unsigned*)nullptr,
                                                      (float*)nullptr, F);
        raster_loss_mono<<<P/256, 256, 0, stream>>>(fd, cols, imref, out, F);
    }
}